// Round 4
// baseline (267.779 us; speedup 1.0000x reference)
//
#include <hip/hip_runtime.h>
#include <hip/hip_bf16.h>

#define Bb 8
#define Nn 128
#define Cc 256
#define SCALE 0.1767766952966369f   // 32^-0.5
#define EPS 1e-5f

typedef short v8s __attribute__((ext_vector_type(8)));
typedef short v4s __attribute__((ext_vector_type(4)));
typedef float v4f __attribute__((ext_vector_type(4)));
using bf16_t = __hip_bfloat16;

__device__ inline float bf2f(bf16_t h){ return __bfloat162float(h); }
__device__ inline short f2bfbits(float f){
    unsigned int u = __float_as_uint(f);
    u += 0x7fff + ((u >> 16) & 1u);        // RNE
    return (short)(u >> 16);
}

// Reduce-scatter 8 values over each 32-lane half: lane l ends with the
// 32-lane total of S[h], h = 4*(l&1) + 2*((l>>1)&1) + ((l>>2)&1).
__device__ inline float rscatter8(const float (&S)[8], int l){
    bool b0 = l & 1, b1 = l & 2, b2 = l & 4;
    float t[4];
#pragma unroll
    for (int k = 0; k < 4; k++){
        float keep = b0 ? S[k+4] : S[k];
        float give = b0 ? S[k]   : S[k+4];
        t[k] = keep + __shfl_xor(give, 1);
    }
    float u[2];
#pragma unroll
    for (int k = 0; k < 2; k++){
        float keep = b1 ? t[k+2] : t[k];
        float give = b1 ? t[k]   : t[k+2];
        u[k] = keep + __shfl_xor(give, 2);
    }
    float r;
    {
        float keep = b2 ? u[1] : u[0];
        float give = b2 ? u[0] : u[1];
        r = keep + __shfl_xor(give, 4);
    }
    r += __shfl_xor(r, 8);
    r += __shfl_xor(r, 16);
    return r;
}

// ---------------------------------------------------------------------------
// K1: fused LayerNorm(relation) + rconv projection -> R[b,n,m,h] (fp32).
// attn_R = rstd*(S_h - mu*T_h) + B_h, W2 = ln2w (x) rconv held in registers.
// One 32-lane half-wave per 256-ch fp32 row (8 floats/lane, 2x dwordx4).
// ---------------------------------------------------------------------------
__global__ __launch_bounds__(256) void relnorm_kernel(
        const float* __restrict__ rel,
        const float* __restrict__ ln2w,
        const float* __restrict__ ln2b,
        const float* __restrict__ rconv,
        float* __restrict__ R)
{
    const int lane = threadIdx.x & 63;
    const int hl = lane & 31;
    const int c0 = hl * 8;

    float w2[8][8];
    float Tp[8] = {0,0,0,0,0,0,0,0};
    float Bp[8] = {0,0,0,0,0,0,0,0};
#pragma unroll
    for (int j = 0; j < 8; j++){
        float lw = ln2w[c0 + j];
        float lb = ln2b[c0 + j];
#pragma unroll
        for (int hh = 0; hh < 8; hh++){
            float rc = rconv[hh * Cc + c0 + j];
            w2[j][hh] = lw * rc;
            Tp[hh] += w2[j][hh];
            Bp[hh] = fmaf(lb, rc, Bp[hh]);
        }
    }
    const float Th = rscatter8(Tp, hl);
    const float Bh = rscatter8(Bp, hl);
    const int h = (hl & 1) * 4 + ((hl >> 1) & 1) * 2 + ((hl >> 2) & 1);

    const int hw = (blockIdx.x * blockDim.x + threadIdx.x) >> 5;
    const int hwStride = (gridDim.x * blockDim.x) >> 5;
    const int totalRows = Bb * Nn * Nn;   // 131072

    for (int row = hw; row < totalRows; row += hwStride){
        const float* rp = rel + (size_t)row * Cc + c0;
        float4 xa = *(const float4*)(rp);
        float4 xb = *(const float4*)(rp + 4);
        float x[8] = { xa.x, xa.y, xa.z, xa.w, xb.x, xb.y, xb.z, xb.w };
        float sum = 0.f, sq = 0.f;
        float S[8] = {0,0,0,0,0,0,0,0};
#pragma unroll
        for (int j = 0; j < 8; j++){
            float xv = x[j];
            sum += xv;
            sq = fmaf(xv, xv, sq);
#pragma unroll
            for (int hh = 0; hh < 8; hh++)
                S[hh] = fmaf(xv, w2[j][hh], S[hh]);
        }
#pragma unroll
        for (int o = 1; o <= 16; o <<= 1){
            sum += __shfl_xor(sum, o);
            sq  += __shfl_xor(sq,  o);
        }
        float mu = sum * (1.f / 256.f);
        float rstd = rsqrtf(sq * (1.f / 256.f) - mu * mu + EPS);
        float Sh = rscatter8(S, hl);
        if (hl < 8)
            R[(size_t)row * 8 + h] = rstd * (Sh - mu * Th) + Bh;
    }
}

// ---------------------------------------------------------------------------
// LayerNorm: fp32 in, fp32 params, bf16 out. One 64-lane wave per row.
// ---------------------------------------------------------------------------
__global__ __launch_bounds__(256) void ln_kernel(
        const float* __restrict__ x, const float* __restrict__ w,
        const float* __restrict__ bv, short* __restrict__ y)
{
    const int lane = threadIdx.x & 63;
    const int row = blockIdx.x * 4 + (threadIdx.x >> 6);
    const int c0 = lane * 4;
    float4 xv4 = *(const float4*)(x + (size_t)row * Cc + c0);
    float xv[4] = { xv4.x, xv4.y, xv4.z, xv4.w };
    float sum = xv[0] + xv[1] + xv[2] + xv[3];
    float sq = fmaf(xv[0], xv[0], fmaf(xv[1], xv[1], fmaf(xv[2], xv[2], xv[3]*xv[3])));
#pragma unroll
    for (int o = 1; o <= 32; o <<= 1){
        sum += __shfl_xor(sum, o);
        sq  += __shfl_xor(sq,  o);
    }
    float mu = sum * (1.f / 256.f);
    float rstd = rsqrtf(sq * (1.f / 256.f) - mu * mu + EPS);
    float4 wv = *(const float4*)(w + c0);
    float4 bb = *(const float4*)(bv + c0);
    v4s o;
    o[0] = f2bfbits((xv[0]-mu)*rstd*wv.x + bb.x);
    o[1] = f2bfbits((xv[1]-mu)*rstd*wv.y + bb.y);
    o[2] = f2bfbits((xv[2]-mu)*rstd*wv.z + bb.z);
    o[3] = f2bfbits((xv[3]-mu)*rstd*wv.w + bb.w);
    *(v4s*)(y + (size_t)row * Cc + c0) = o;
}

// ---------------------------------------------------------------------------
// MFMA GEMM: D[m,n] = sum_k A[m,k]*W[n,k]; A bf16, W fp32 (cvt in-reg), K=256.
// Block: 4 waves -> 16m x 64n. EPI: 0 ->bf16; 1 +bias+f32res->fp32;
// 2 +bias+GELU->bf16; 3 +bias+f32res->fp32 (final output).
// ---------------------------------------------------------------------------
template<int NTOT, int EPI>
__global__ __launch_bounds__(256) void gemm_kernel(
        const bf16_t* __restrict__ A, const float* __restrict__ W,
        const float* __restrict__ bias, const float* __restrict__ res,
        void* __restrict__ out)
{
    const int lane = threadIdx.x & 63;
    const int wv = threadIdx.x >> 6;
    const int mtile = blockIdx.x * 16;
    const int ntile = blockIdx.y * 64 + wv * 16;
    const int mi = lane & 15, q = lane >> 4;
    const bf16_t* ap = A + (size_t)(mtile + mi) * Cc + q * 8;
    const float* wp = W + (size_t)(ntile + mi) * Cc + q * 8;
    v4f acc = {0.f, 0.f, 0.f, 0.f};
#pragma unroll
    for (int kk = 0; kk < 8; kk++){
        v8s af = *(const v8s*)(ap + kk * 32);
        float4 w0 = *(const float4*)(wp + kk * 32);
        float4 w1 = *(const float4*)(wp + kk * 32 + 4);
        v8s bf;
        bf[0]=f2bfbits(w0.x); bf[1]=f2bfbits(w0.y); bf[2]=f2bfbits(w0.z); bf[3]=f2bfbits(w0.w);
        bf[4]=f2bfbits(w1.x); bf[5]=f2bfbits(w1.y); bf[6]=f2bfbits(w1.z); bf[7]=f2bfbits(w1.w);
        acc = __builtin_amdgcn_mfma_f32_16x16x32_bf16(af, bf, acc, 0, 0, 0);
    }
    const int n = ntile + mi;
    float bia = (EPI > 0) ? bias[n] : 0.f;
#pragma unroll
    for (int r = 0; r < 4; r++){
        int m = mtile + q * 4 + r;
        float v = acc[r] + bia;
        if (EPI == 0){
            ((short*)out)[(size_t)m * NTOT + n] = f2bfbits(v);
        } else if (EPI == 1){
            v += res[(size_t)m * Cc + n];
            ((float*)out)[(size_t)m * Cc + n] = v;
        } else if (EPI == 2){
            v = 0.5f * v * (1.f + erff(v * 0.70710678118654752f));
            ((short*)out)[(size_t)m * Cc + n] = f2bfbits(v);
        } else {
            // final: fp32 residual add, fp32 OUTPUT (reference output dtype!)
            v += res[(size_t)m * Cc + n];
            ((float*)out)[(size_t)m * Cc + n] = v;
        }
    }
}

// ---------------------------------------------------------------------------
// Attention: one block per (b,h,n-quarter). K/V/Q staged in LDS (fp32);
// scores=(q.k+R)*conn*SCALE; softmax over m; out = P @ V -> bf16.
// ---------------------------------------------------------------------------
__global__ __launch_bounds__(256) void attn_kernel(
        const bf16_t* __restrict__ qkv,    // [1024][768] bf16
        const float* __restrict__ R,       // [b][n][m][h] fp32
        const float* __restrict__ conn,    // [b][n][m] fp32
        short* __restrict__ xatt)          // [b][n][256] bf16
{
    const int bid = blockIdx.x;            // 256 blocks
    const int b = bid >> 5;
    const int h = (bid >> 2) & 7;
    const int nq = bid & 3;
    __shared__ float k_s[128 * 36];        // [m][d], pad to 36 (16B-aligned rows)
    __shared__ float v_s[128 * 32];        // [m][d]
    __shared__ float q_s[32 * 33];         // [nl][d]
    __shared__ float p_s[32 * 132];        // [nl][m]
    const int t = threadIdx.x;
    const bf16_t* qkvb = qkv + (size_t)b * Nn * 768;

#pragma unroll
    for (int i = 0; i < 16; i++){
        int idx = t + i * 256;
        int m = idx >> 5, d = idx & 31;
        k_s[m * 36 + d] = bf2f(qkvb[m * 768 + 256 + h * 32 + d]);
        v_s[m * 32 + d] = bf2f(qkvb[m * 768 + 512 + h * 32 + d]);
    }
#pragma unroll
    for (int i = 0; i < 4; i++){
        int idx = t + i * 256;
        int nl = idx >> 5, d = idx & 31;
        q_s[nl * 33 + d] = bf2f(qkvb[(nq * 32 + nl) * 768 + h * 32 + d]);
    }
    __syncthreads();

    const int nl = t >> 3, tg = t & 7;
    const int n = nq * 32 + nl;
    float qr[32];
#pragma unroll
    for (int d = 0; d < 32; d++) qr[d] = q_s[nl * 33 + d];
    const float* Rrow = R + ((size_t)(b * Nn + n) * Nn) * 8 + h;
    const float* crow = conn + (size_t)(b * Nn + n) * Nn;

    float s[16];
#pragma unroll
    for (int i = 0; i < 16; i++){
        int m = tg + 8 * i;
        float acc = 0.f;
#pragma unroll
        for (int g = 0; g < 8; g++){
            float4 kv = *(const float4*)&k_s[m * 36 + g * 4];
            acc = fmaf(qr[g*4+0], kv.x, acc);
            acc = fmaf(qr[g*4+1], kv.y, acc);
            acc = fmaf(qr[g*4+2], kv.z, acc);
            acc = fmaf(qr[g*4+3], kv.w, acc);
        }
        s[i] = (acc + Rrow[(size_t)m * 8]) * crow[m] * SCALE;
    }
    float mx = s[0];
#pragma unroll
    for (int i = 1; i < 16; i++) mx = fmaxf(mx, s[i]);
    mx = fmaxf(mx, __shfl_xor(mx, 1));
    mx = fmaxf(mx, __shfl_xor(mx, 2));
    mx = fmaxf(mx, __shfl_xor(mx, 4));
    float lsum = 0.f;
#pragma unroll
    for (int i = 0; i < 16; i++){ s[i] = expf(s[i] - mx); lsum += s[i]; }
    lsum += __shfl_xor(lsum, 1);
    lsum += __shfl_xor(lsum, 2);
    lsum += __shfl_xor(lsum, 4);
    float inv = 1.f / lsum;
#pragma unroll
    for (int i = 0; i < 16; i++)
        p_s[nl * 132 + tg + 8 * i] = s[i] * inv;
    __syncthreads();

    const int d0 = tg * 4;
    float a0 = 0.f, a1 = 0.f, a2 = 0.f, a3 = 0.f;
    for (int m = 0; m < 128; m++){
        float p = p_s[nl * 132 + m];
        float4 vv = *(const float4*)&v_s[m * 32 + d0];
        a0 = fmaf(p, vv.x, a0);
        a1 = fmaf(p, vv.y, a1);
        a2 = fmaf(p, vv.z, a2);
        a3 = fmaf(p, vv.w, a3);
    }
    v4s o4; o4[0]=f2bfbits(a0); o4[1]=f2bfbits(a1); o4[2]=f2bfbits(a2); o4[3]=f2bfbits(a3);
    *(v4s*)(xatt + (size_t)(b * Nn + n) * Cc + h * 32 + d0) = o4;
}

// ---------------------------------------------------------------------------
extern "C" void kernel_launch(void* const* d_in, const int* in_sizes, int n_in,
                              void* d_out, int out_size, void* d_ws, size_t ws_size,
                              hipStream_t stream)
{
    // All reference inputs AND the output are float32.
    const float* joint  = (const float*)d_in[0];
    const float* rel    = (const float*)d_in[1];
    const float* conn   = (const float*)d_in[2];
    const float* ln1w   = (const float*)d_in[3];
    const float* ln1b   = (const float*)d_in[4];
    const float* ln2w   = (const float*)d_in[5];
    const float* ln2b   = (const float*)d_in[6];
    const float* ln3w   = (const float*)d_in[7];
    const float* ln3b   = (const float*)d_in[8];
    const float* qkvw   = (const float*)d_in[9];
    const float* rconv  = (const float*)d_in[10];
    const float* projw  = (const float*)d_in[11];
    const float* projb  = (const float*)d_in[12];
    const float* fc1w   = (const float*)d_in[13];
    const float* fc1b   = (const float*)d_in[14];
    const float* fc2w   = (const float*)d_in[15];
    const float* fc2b   = (const float*)d_in[16];

    // ws layout (byte offsets), total 8.5 MB
    char* w = (char*)d_ws;
    float* Rf     = (float*)(w);                   // 131072*8 f32 = 4 MB
    short* qkvb   = (short*)(w + 4194304);         // 1024*768 bf16 = 1.5 MB
    short* jnb    = (short*)(w + 5767168);         // 1024*256 bf16 = 0.5 MB
    short* xattb  = (short*)(w + 6291456);         // 0.5 MB
    float* joint2 = (float*)(w + 6815744);         // 1024*256 f32 = 1 MB
    short* h1b    = (short*)(w + 7864320);         // 0.5 MB
    short* h2b    = (short*)(w + 8388608);         // 0.5 MB -> ends 8912896

    relnorm_kernel<<<dim3(2048), dim3(256), 0, stream>>>(rel, ln2w, ln2b, rconv, Rf);
    ln_kernel<<<dim3(256), dim3(256), 0, stream>>>(joint, ln1w, ln1b, jnb);
    gemm_kernel<768, 0><<<dim3(64, 12), dim3(256), 0, stream>>>(
        (const bf16_t*)jnb, qkvw, nullptr, nullptr, qkvb);
    attn_kernel<<<dim3(256), dim3(256), 0, stream>>>(
        (const bf16_t*)qkvb, Rf, conn, xattb);
    gemm_kernel<256, 1><<<dim3(64, 4), dim3(256), 0, stream>>>(
        (const bf16_t*)xattb, projw, projb, joint, joint2);
    ln_kernel<<<dim3(256), dim3(256), 0, stream>>>(joint2, ln3w, ln3b, h1b);
    gemm_kernel<256, 2><<<dim3(64, 4), dim3(256), 0, stream>>>(
        (const bf16_t*)h1b, fc1w, fc1b, nullptr, h2b);
    gemm_kernel<256, 3><<<dim3(64, 4), dim3(256), 0, stream>>>(
        (const bf16_t*)h2b, fc2w, fc2b, joint2, (float*)d_out);
}

// Round 5
// 257.517 us; speedup vs baseline: 1.0398x; 1.0398x over previous
//
#include <hip/hip_runtime.h>
#include <hip/hip_bf16.h>

#define Bb 8
#define Nn 128
#define Cc 256
#define SCALE 0.1767766952966369f   // 32^-0.5
#define EPS 1e-5f

typedef short v8s __attribute__((ext_vector_type(8)));
typedef short v4s __attribute__((ext_vector_type(4)));
typedef float v4f __attribute__((ext_vector_type(4)));
using bf16_t = __hip_bfloat16;

__device__ inline float bf2f(bf16_t h){ return __bfloat162float(h); }
__device__ inline short f2bfbits(float f){
    unsigned int u = __float_as_uint(f);
    u += 0x7fff + ((u >> 16) & 1u);        // RNE
    return (short)(u >> 16);
}

// Reduce-scatter 8 values over each 32-lane half: lane l ends with the
// 32-lane total of S[h], h = 4*(l&1) + 2*((l>>1)&1) + ((l>>2)&1).
__device__ inline float rscatter8(const float (&S)[8], int l){
    bool b0 = l & 1, b1 = l & 2, b2 = l & 4;
    float t[4];
#pragma unroll
    for (int k = 0; k < 4; k++){
        float keep = b0 ? S[k+4] : S[k];
        float give = b0 ? S[k]   : S[k+4];
        t[k] = keep + __shfl_xor(give, 1);
    }
    float u[2];
#pragma unroll
    for (int k = 0; k < 2; k++){
        float keep = b1 ? t[k+2] : t[k];
        float give = b1 ? t[k]   : t[k+2];
        u[k] = keep + __shfl_xor(give, 2);
    }
    float r;
    {
        float keep = b2 ? u[1] : u[0];
        float give = b2 ? u[0] : u[1];
        r = keep + __shfl_xor(give, 4);
    }
    r += __shfl_xor(r, 8);
    r += __shfl_xor(r, 16);
    return r;
}

// ---------------------------------------------------------------------------
// LN+GEMM body: per-block, stage A-tile [16 rows][256] fp32 -> row-LN ->
// bf16 LDS tile -> MFMA against W[n][k] fp32 (cvt in-reg).
// EPI 0: plain -> bf16 out [m][NTOT]; EPI 2: +bias, exact GELU -> bf16 [m][256]
// ---------------------------------------------------------------------------
template<int NTOT, int EPI>
__device__ __forceinline__ void lngemm_body(
        const float* __restrict__ A, const float* __restrict__ lnw,
        const float* __restrict__ lnb, const float* __restrict__ W,
        const float* __restrict__ bias, short* __restrict__ out,
        int mtile, int ntile0)
{
    __shared__ short a_s[16][264];         // bf16 normalized tile (row 528 B)
    __shared__ float red[2][16][16];
    const int t = threadIdx.x;
    const int r = t >> 4, j = t & 15;      // 16 threads per row, 16 elems each
    const float* rowp = A + (size_t)(mtile + r) * Cc + j * 16;
    float x[16];
#pragma unroll
    for (int i = 0; i < 4; i++){
        float4 v = *(const float4*)(rowp + i * 4);
        x[i*4+0]=v.x; x[i*4+1]=v.y; x[i*4+2]=v.z; x[i*4+3]=v.w;
    }
    float s1 = 0.f, s2 = 0.f;
#pragma unroll
    for (int i = 0; i < 16; i++){ s1 += x[i]; s2 = fmaf(x[i], x[i], s2); }
    red[0][r][j] = s1; red[1][r][j] = s2;
    __syncthreads();
    float t1 = 0.f, t2 = 0.f;
#pragma unroll
    for (int i = 0; i < 16; i++){ t1 += red[0][r][i]; t2 += red[1][r][i]; }
    const float mu = t1 * (1.f/256.f);
    const float rstd = rsqrtf(t2 * (1.f/256.f) - mu*mu + EPS);
    short pk[16];
#pragma unroll
    for (int i = 0; i < 4; i++){
        float4 wv4 = *(const float4*)(lnw + j*16 + i*4);
        float4 bv4 = *(const float4*)(lnb + j*16 + i*4);
        pk[i*4+0] = f2bfbits((x[i*4+0]-mu)*rstd*wv4.x + bv4.x);
        pk[i*4+1] = f2bfbits((x[i*4+1]-mu)*rstd*wv4.y + bv4.y);
        pk[i*4+2] = f2bfbits((x[i*4+2]-mu)*rstd*wv4.z + bv4.z);
        pk[i*4+3] = f2bfbits((x[i*4+3]-mu)*rstd*wv4.w + bv4.w);
    }
    *(v8s*)&a_s[r][j*16]     = *(v8s*)&pk[0];
    *(v8s*)&a_s[r][j*16 + 8] = *(v8s*)&pk[8];
    __syncthreads();

    const int lane = t & 63;
    const int wv = t >> 6;
    const int ntile = ntile0 + wv * 16;
    const int mi = lane & 15, q = lane >> 4;
    const short* alds = &a_s[mi][q * 8];
    const float* wp = W + (size_t)(ntile + mi) * Cc + q * 8;
    v4f acc = {0.f, 0.f, 0.f, 0.f};
#pragma unroll
    for (int kk = 0; kk < 8; kk++){
        v8s af = *(const v8s*)(alds + kk * 32);
        float4 w0 = *(const float4*)(wp + kk * 32);
        float4 w1 = *(const float4*)(wp + kk * 32 + 4);
        v8s bf;
        bf[0]=f2bfbits(w0.x); bf[1]=f2bfbits(w0.y); bf[2]=f2bfbits(w0.z); bf[3]=f2bfbits(w0.w);
        bf[4]=f2bfbits(w1.x); bf[5]=f2bfbits(w1.y); bf[6]=f2bfbits(w1.z); bf[7]=f2bfbits(w1.w);
        acc = __builtin_amdgcn_mfma_f32_16x16x32_bf16(af, bf, acc, 0, 0, 0);
    }
    const int n = ntile + mi;
    const float bia = (EPI == 2) ? bias[n] : 0.f;
#pragma unroll
    for (int rr = 0; rr < 4; rr++){
        int m = mtile + q * 4 + rr;
        float v = acc[rr] + bia;
        if (EPI == 2) v = 0.5f * v * (1.f + erff(v * 0.70710678118654752f));
        out[(size_t)m * NTOT + n] = f2bfbits(v);
    }
}

// ---------------------------------------------------------------------------
// K1 mega-kernel. Blocks [0,2048): fused LayerNorm(relation)+rconv -> R bf16.
// Blocks [2048,2816): LN1+QKV gemm (independent of relnorm).
// ---------------------------------------------------------------------------
__global__ __launch_bounds__(256) void mega1_kernel(
        const float* __restrict__ rel,
        const float* __restrict__ ln2w, const float* __restrict__ ln2b,
        const float* __restrict__ rconv, short* __restrict__ R,
        const float* __restrict__ joint,
        const float* __restrict__ ln1w, const float* __restrict__ ln1b,
        const float* __restrict__ qkvw, short* __restrict__ qkvb)
{
    if (blockIdx.x >= 2048){
        const int bx = blockIdx.x - 2048;           // 0..767
        lngemm_body<768, 0>(joint, ln1w, ln1b, qkvw, nullptr, qkvb,
                            (bx & 63) * 16, (bx >> 6) * 64);
        return;
    }
    const int lane = threadIdx.x & 63;
    const int hl = lane & 31;
    const int c0 = hl * 8;

    float w2[8][8];
    float Tp[8] = {0,0,0,0,0,0,0,0};
    float Bp[8] = {0,0,0,0,0,0,0,0};
#pragma unroll
    for (int j = 0; j < 8; j++){
        float lw = ln2w[c0 + j];
        float lb = ln2b[c0 + j];
#pragma unroll
        for (int hh = 0; hh < 8; hh++){
            float rc = rconv[hh * Cc + c0 + j];
            w2[j][hh] = lw * rc;
            Tp[hh] += w2[j][hh];
            Bp[hh] = fmaf(lb, rc, Bp[hh]);
        }
    }
    const float Th = rscatter8(Tp, hl);
    const float Bh = rscatter8(Bp, hl);
    const int h = (hl & 1) * 4 + ((hl >> 1) & 1) * 2 + ((hl >> 2) & 1);

    const int hw = (blockIdx.x * 256 + threadIdx.x) >> 5;
    const int hwStride = (2048 * 256) >> 5;        // 16384 (relnorm range only)
    const int totalRows = Bb * Nn * Nn;            // 131072

    for (int row = hw; row < totalRows; row += hwStride){
        const float* rp = rel + (size_t)row * Cc + c0;
        float4 xa = *(const float4*)(rp);
        float4 xb = *(const float4*)(rp + 4);
        float x[8] = { xa.x, xa.y, xa.z, xa.w, xb.x, xb.y, xb.z, xb.w };
        float sum = 0.f, sq = 0.f;
        float S[8] = {0,0,0,0,0,0,0,0};
#pragma unroll
        for (int j = 0; j < 8; j++){
            float xv = x[j];
            sum += xv;
            sq = fmaf(xv, xv, sq);
#pragma unroll
            for (int hh = 0; hh < 8; hh++)
                S[hh] = fmaf(xv, w2[j][hh], S[hh]);
        }
#pragma unroll
        for (int o = 1; o <= 16; o <<= 1){
            sum += __shfl_xor(sum, o);
            sq  += __shfl_xor(sq,  o);
        }
        float mu = sum * (1.f / 256.f);
        float rstd = rsqrtf(sq * (1.f / 256.f) - mu * mu + EPS);
        float Sh = rscatter8(S, hl);
        if (hl < 8)
            R[(size_t)row * 8 + h] = f2bfbits(rstd * (Sh - mu * Th) + Bh);
    }
}

// ---------------------------------------------------------------------------
// MFMA GEMM (no LN): D[m,n] = sum_k A[m,k]*W[n,k]; A bf16, W fp32.
// EPI 1: +bias +fp32res -> fp32; EPI 3: +bias +fp32res -> fp32 (d_out).
// ---------------------------------------------------------------------------
template<int EPI>
__global__ __launch_bounds__(256) void gemm_kernel(
        const bf16_t* __restrict__ A, const float* __restrict__ W,
        const float* __restrict__ bias, const float* __restrict__ res,
        float* __restrict__ out)
{
    const int lane = threadIdx.x & 63;
    const int wv = threadIdx.x >> 6;
    const int mtile = blockIdx.x * 16;
    const int ntile = blockIdx.y * 64 + wv * 16;
    const int mi = lane & 15, q = lane >> 4;
    const bf16_t* ap = A + (size_t)(mtile + mi) * Cc + q * 8;
    const float* wp = W + (size_t)(ntile + mi) * Cc + q * 8;
    v4f acc = {0.f, 0.f, 0.f, 0.f};
#pragma unroll
    for (int kk = 0; kk < 8; kk++){
        v8s af = *(const v8s*)(ap + kk * 32);
        float4 w0 = *(const float4*)(wp + kk * 32);
        float4 w1 = *(const float4*)(wp + kk * 32 + 4);
        v8s bf;
        bf[0]=f2bfbits(w0.x); bf[1]=f2bfbits(w0.y); bf[2]=f2bfbits(w0.z); bf[3]=f2bfbits(w0.w);
        bf[4]=f2bfbits(w1.x); bf[5]=f2bfbits(w1.y); bf[6]=f2bfbits(w1.z); bf[7]=f2bfbits(w1.w);
        acc = __builtin_amdgcn_mfma_f32_16x16x32_bf16(af, bf, acc, 0, 0, 0);
    }
    const int n = ntile + mi;
    const float bia = bias[n];
#pragma unroll
    for (int r = 0; r < 4; r++){
        int m = mtile + q * 4 + r;
        float v = acc[r] + bia + res[(size_t)m * Cc + n];
        out[(size_t)m * Cc + n] = v;
    }
}

__global__ __launch_bounds__(256) void fc1_kernel(
        const float* __restrict__ joint2,
        const float* __restrict__ ln3w, const float* __restrict__ ln3b,
        const float* __restrict__ fc1w, const float* __restrict__ fc1b,
        short* __restrict__ h2)
{
    lngemm_body<256, 2>(joint2, ln3w, ln3b, fc1w, fc1b, h2,
                        blockIdx.x * 16, blockIdx.y * 64);
}

// ---------------------------------------------------------------------------
// Attention: one block per (b,h,n-quarter). K/V/Q staged in LDS (fp32);
// scores=(q.k+R)*conn*SCALE; softmax over m; out = P @ V -> bf16.
// ---------------------------------------------------------------------------
__global__ __launch_bounds__(256) void attn_kernel(
        const bf16_t* __restrict__ qkv,    // [1024][768] bf16
        const bf16_t* __restrict__ R,      // [b][n][m][h] bf16
        const float* __restrict__ conn,    // [b][n][m] fp32
        short* __restrict__ xatt)          // [b][n][256] bf16
{
    const int bid = blockIdx.x;            // 256 blocks
    const int b = bid >> 5;
    const int h = (bid >> 2) & 7;
    const int nq = bid & 3;
    __shared__ float k_s[128 * 36];        // [m][d], pad 36 (16B-aligned rows)
    __shared__ float v_s[128 * 32];        // [m][d]
    __shared__ float q_s[32 * 33];         // [nl][d]
    __shared__ float p_s[32 * 132];        // [nl][m]
    const int t = threadIdx.x;
    const bf16_t* qkvb = qkv + (size_t)b * Nn * 768;

#pragma unroll
    for (int i = 0; i < 16; i++){
        int idx = t + i * 256;
        int m = idx >> 5, d = idx & 31;
        k_s[m * 36 + d] = bf2f(qkvb[m * 768 + 256 + h * 32 + d]);
        v_s[m * 32 + d] = bf2f(qkvb[m * 768 + 512 + h * 32 + d]);
    }
#pragma unroll
    for (int i = 0; i < 4; i++){
        int idx = t + i * 256;
        int nl = idx >> 5, d = idx & 31;
        q_s[nl * 33 + d] = bf2f(qkvb[(nq * 32 + nl) * 768 + h * 32 + d]);
    }
    __syncthreads();

    const int nl = t >> 3, tg = t & 7;
    const int n = nq * 32 + nl;
    float qr[32];
#pragma unroll
    for (int d = 0; d < 32; d++) qr[d] = q_s[nl * 33 + d];
    const bf16_t* Rrow = R + ((size_t)(b * Nn + n) * Nn) * 8 + h;
    const float* crow = conn + (size_t)(b * Nn + n) * Nn;

    float s[16];
#pragma unroll
    for (int i = 0; i < 16; i++){
        int m = tg + 8 * i;
        float acc = 0.f;
#pragma unroll
        for (int g = 0; g < 8; g++){
            float4 kv = *(const float4*)&k_s[m * 36 + g * 4];
            acc = fmaf(qr[g*4+0], kv.x, acc);
            acc = fmaf(qr[g*4+1], kv.y, acc);
            acc = fmaf(qr[g*4+2], kv.z, acc);
            acc = fmaf(qr[g*4+3], kv.w, acc);
        }
        s[i] = (acc + bf2f(Rrow[(size_t)m * 8])) * crow[m] * SCALE;
    }
    float mx = s[0];
#pragma unroll
    for (int i = 1; i < 16; i++) mx = fmaxf(mx, s[i]);
    mx = fmaxf(mx, __shfl_xor(mx, 1));
    mx = fmaxf(mx, __shfl_xor(mx, 2));
    mx = fmaxf(mx, __shfl_xor(mx, 4));
    float lsum = 0.f;
#pragma unroll
    for (int i = 0; i < 16; i++){ s[i] = expf(s[i] - mx); lsum += s[i]; }
    lsum += __shfl_xor(lsum, 1);
    lsum += __shfl_xor(lsum, 2);
    lsum += __shfl_xor(lsum, 4);
    float inv = 1.f / lsum;
#pragma unroll
    for (int i = 0; i < 16; i++)
        p_s[nl * 132 + tg + 8 * i] = s[i] * inv;
    __syncthreads();

    const int d0 = tg * 4;
    float a0 = 0.f, a1 = 0.f, a2 = 0.f, a3 = 0.f;
    for (int m = 0; m < 128; m++){
        float p = p_s[nl * 132 + m];
        float4 vv = *(const float4*)&v_s[m * 32 + d0];
        a0 = fmaf(p, vv.x, a0);
        a1 = fmaf(p, vv.y, a1);
        a2 = fmaf(p, vv.z, a2);
        a3 = fmaf(p, vv.w, a3);
    }
    v4s o4; o4[0]=f2bfbits(a0); o4[1]=f2bfbits(a1); o4[2]=f2bfbits(a2); o4[3]=f2bfbits(a3);
    *(v4s*)(xatt + (size_t)(b * Nn + n) * Cc + h * 32 + d0) = o4;
}

// ---------------------------------------------------------------------------
extern "C" void kernel_launch(void* const* d_in, const int* in_sizes, int n_in,
                              void* d_out, int out_size, void* d_ws, size_t ws_size,
                              hipStream_t stream)
{
    const float* joint  = (const float*)d_in[0];
    const float* rel    = (const float*)d_in[1];
    const float* conn   = (const float*)d_in[2];
    const float* ln1w   = (const float*)d_in[3];
    const float* ln1b   = (const float*)d_in[4];
    const float* ln2w   = (const float*)d_in[5];
    const float* ln2b   = (const float*)d_in[6];
    const float* ln3w   = (const float*)d_in[7];
    const float* ln3b   = (const float*)d_in[8];
    const float* qkvw   = (const float*)d_in[9];
    const float* rconv  = (const float*)d_in[10];
    const float* projw  = (const float*)d_in[11];
    const float* projb  = (const float*)d_in[12];
    const float* fc1w   = (const float*)d_in[13];
    const float* fc1b   = (const float*)d_in[14];
    const float* fc2w   = (const float*)d_in[15];
    const float* fc2b   = (const float*)d_in[16];

    // ws layout (byte offsets), total 5.5 MB
    char* w = (char*)d_ws;
    short* Rb     = (short*)(w);                   // 131072*8 bf16 = 2 MB
    short* qkvb   = (short*)(w + 2097152);         // 1024*768 bf16 = 1.5 MB
    short* xattb  = (short*)(w + 3670016);         // 1024*256 bf16 = 0.5 MB
    float* joint2 = (float*)(w + 4194304);         // 1024*256 f32  = 1 MB
    short* h2b    = (short*)(w + 5242880);         // 0.5 MB -> ends 5767168

    // K1: relnorm (blocks 0..2047) + LN1+QKV (blocks 2048..2815)
    mega1_kernel<<<dim3(2816), dim3(256), 0, stream>>>(
        rel, ln2w, ln2b, rconv, Rb, joint, ln1w, ln1b, qkvw, qkvb);
    // K2: attention
    attn_kernel<<<dim3(256), dim3(256), 0, stream>>>(
        (const bf16_t*)qkvb, (const bf16_t*)Rb, conn, xattb);
    // K3: proj + bias + joint residual -> joint2 fp32
    gemm_kernel<1><<<dim3(64, 4), dim3(256), 0, stream>>>(
        (const bf16_t*)xattb, projw, projb, joint, joint2);
    // K4: LN3 + fc1 + bias + GELU -> h2 bf16
    fc1_kernel<<<dim3(64, 4), dim3(256), 0, stream>>>(
        joint2, ln3w, ln3b, fc1w, fc1b, h2b);
    // K5: fc2 + bias + joint2 residual -> d_out fp32
    gemm_kernel<3><<<dim3(64, 4), dim3(256), 0, stream>>>(
        (const bf16_t*)h2b, fc2w, fc2b, joint2, (float*)d_out);
}